// Round 16
// baseline (569.354 us; speedup 1.0000x reference)
//
#include <hip/hip_runtime.h>

// GCN sparse conv: out = relu( sparse(adj) @ ( sparse(x) @ W ) )
// Bucket counting sort (256 rows/bucket):
//   bhist2:    LDS bucket histogram, int4-vectorized row loads (+W->bf16)
//   bscan2:    exclusive scan of bucket counts -> bases + cursors
//   bscatter2: 4096-edge chunks (grid split x|adj); int4/float4 COO reads;
//              LDS hist -> ONE global fetch-add per (block,bucket); LDS
//              re-rank; coalesced flush to bucket-grouped q.
//   bfinalX:   per-bucket finalize for x -> CSR offsets + packed 4B edges
//   fusedAS:   grid = {bfinal-adj blocks | spmm1 blocks} -- adj finalize
//              overlaps spmm1 (spmm1 depends only on x-side).
//   spmm2:     wave per row, lane owns 4 cols, 8-deep unroll (R10 shape:
//              best measured 217us/747MB; gather service-rate bound ~3.4TB/s).
// Edge words 4B: x = col<<16 | bf16(val); adj = col<<15 | bf15(val>=0).
// xw bf16 plain stores (L2-warm for spmm2); NT store only for final out.

constexpr int OUT_DIM = 256;
constexpr int RPB     = 256;     // rows per bucket
constexpr int RPB_SH  = 8;
constexpr int MAXB    = 1024;    // max buckets (N <= 262144)
constexpr int CHUNK   = 4096;    // edges per bscatter block

typedef float        f32x4 __attribute__((ext_vector_type(4)));
typedef unsigned int u32x2 __attribute__((ext_vector_type(2)));
typedef int          i32x4 __attribute__((ext_vector_type(4)));

static __device__ __forceinline__ unsigned f2bf(float f) {
    unsigned u = __float_as_uint(f);
    return (u + 0x7FFFu + ((u >> 16) & 1u)) >> 16;   // round-nearest-even
}
static __device__ __forceinline__ float blo(unsigned w) { return __uint_as_float(w << 16); }
static __device__ __forceinline__ float bhi(unsigned w) { return __uint_as_float(w & 0xFFFF0000u); }

// ------- bucket histogram (both matrices, vectorized) + W->bf16 -------

__global__ void bhist2(const int* __restrict__ xr, int nx,
                       const int* __restrict__ ar, int na,
                       int* __restrict__ bcx, int* __restrict__ bca,
                       const float* __restrict__ W, u32x2* __restrict__ Wb,
                       int n_wb, int nbk) {
    __shared__ int hx[MAXB], ha[MAXB];
    const int t = (int)threadIdx.x;
    for (int j = t; j < nbk; j += 256) { hx[j] = 0; ha[j] = 0; }
    __syncthreads();
    const int gid = (int)(blockIdx.x * blockDim.x + threadIdx.x);
    const int stride = (int)(gridDim.x * blockDim.x);
    const int nx4 = nx >> 2, na4 = na >> 2;
    for (int i = gid; i < nx4; i += stride) {
        const i32x4 r = __builtin_nontemporal_load(reinterpret_cast<const i32x4*>(xr) + i);
        atomicAdd(&hx[r.x >> RPB_SH], 1); atomicAdd(&hx[r.y >> RPB_SH], 1);
        atomicAdd(&hx[r.z >> RPB_SH], 1); atomicAdd(&hx[r.w >> RPB_SH], 1);
    }
    for (int i = nx4 * 4 + gid; i < nx; i += stride) atomicAdd(&hx[xr[i] >> RPB_SH], 1);
    for (int i = gid; i < na4; i += stride) {
        const i32x4 r = __builtin_nontemporal_load(reinterpret_cast<const i32x4*>(ar) + i);
        atomicAdd(&ha[r.x >> RPB_SH], 1); atomicAdd(&ha[r.y >> RPB_SH], 1);
        atomicAdd(&ha[r.z >> RPB_SH], 1); atomicAdd(&ha[r.w >> RPB_SH], 1);
    }
    for (int i = na4 * 4 + gid; i < na; i += stride) atomicAdd(&ha[ar[i] >> RPB_SH], 1);
    for (int i = gid; i < n_wb; i += stride) {
        const float4 w = reinterpret_cast<const float4*>(W)[i];
        u32x2 o;
        o.x = f2bf(w.x) | (f2bf(w.y) << 16);
        o.y = f2bf(w.z) | (f2bf(w.w) << 16);
        Wb[i] = o;
    }
    __syncthreads();
    for (int j = t; j < nbk; j += 256) {
        if (hx[j]) atomicAdd(&bcx[j], hx[j]);
        if (ha[j]) atomicAdd(&bca[j], ha[j]);
    }
}

// ------- exclusive scan of bucket counts (in place) + cursor init -------

__global__ void bscan2(int* __restrict__ bx, int* __restrict__ ba,
                       int* __restrict__ gx, int* __restrict__ ga, int nbk) {
    __shared__ int sh[MAXB];
    int* bs = (blockIdx.x == 0) ? bx : ba;
    int* gc = (blockIdx.x == 0) ? gx : ga;
    const int t = (int)threadIdx.x;
    const int v = (t < nbk) ? bs[t] : 0;
    sh[t] = v;
    __syncthreads();
    for (int off = 1; off < MAXB; off <<= 1) {
        int cur = sh[t];
        int a = (t >= off) ? sh[t - off] : 0;
        __syncthreads();
        sh[t] = cur + a;
        __syncthreads();
    }
    if (t < nbk) {
        const int e = sh[t] - v;   // exclusive
        bs[t] = e;
        gc[t] = e;
    }
}

// ------- aggregated bucket scatter (grid split x | adj), vectorized reads -------
// q entry: .x = rowInBucket(8b)<<17 | col(17b);  .y = f32 val bits.

static __device__ __forceinline__ void bscatter_body(
        const int* __restrict__ rows, const int* __restrict__ cols,
        const float* __restrict__ vals, int* __restrict__ gcur,
        u32x2* __restrict__ q, int nnz, int nbk, int blk) {
    __shared__ u32x2 stage[CHUNK];
    __shared__ int   saddr[CHUNK];
    __shared__ int   lcnt[MAXB], lstart[MAXB], gstart[MAXB];
    __shared__ int   ssum[256];
    const int t    = (int)threadIdx.x;
    const int base = blk * CHUNK;
    const int cnt  = min(CHUNK, nnz - base);

    for (int j = t; j < nbk; j += 256) lcnt[j] = 0;
    __syncthreads();

    int   rr[16] __attribute__((aligned(16)));
    int   cc[16] __attribute__((aligned(16)));
    float vv[16] __attribute__((aligned(16)));
    unsigned ex[16], ey[16];
    int my[16], bk[16];
    const int i0 = base + t * 16;
    if (i0 + 16 <= nnz) {
        #pragma unroll
        for (int g = 0; g < 4; ++g) {
            reinterpret_cast<i32x4*>(rr)[g] =
                __builtin_nontemporal_load(reinterpret_cast<const i32x4*>(rows + i0) + g);
            reinterpret_cast<i32x4*>(cc)[g] =
                __builtin_nontemporal_load(reinterpret_cast<const i32x4*>(cols + i0) + g);
            reinterpret_cast<f32x4*>(vv)[g] =
                __builtin_nontemporal_load(reinterpret_cast<const f32x4*>(vals + i0) + g);
        }
    } else {
        #pragma unroll
        for (int k = 0; k < 16; ++k) {
            if (i0 + k < nnz) { rr[k] = rows[i0 + k]; cc[k] = cols[i0 + k]; vv[k] = vals[i0 + k]; }
            else              { rr[k] = 0; cc[k] = 0; vv[k] = 0.f; }
        }
    }
    #pragma unroll
    for (int k = 0; k < 16; ++k) {
        bk[k] = -1;
        if (i0 + k < nnz) {
            const int r = rr[k];
            bk[k] = r >> RPB_SH;
            ex[k] = ((unsigned)(r & (RPB - 1)) << 17) | (unsigned)cc[k];
            ey[k] = __float_as_uint(vv[k]);
            my[k] = atomicAdd(&lcnt[bk[k]], 1);
        }
    }
    __syncthreads();

    {   // local exclusive scan of lcnt -> lstart (4 elems/thread)
        const int idx = t * 4;
        const int c0 = (idx + 0 < nbk) ? lcnt[idx + 0] : 0;
        const int c1 = (idx + 1 < nbk) ? lcnt[idx + 1] : 0;
        const int c2 = (idx + 2 < nbk) ? lcnt[idx + 2] : 0;
        const int c3 = (idx + 3 < nbk) ? lcnt[idx + 3] : 0;
        const int tsum = c0 + c1 + c2 + c3;
        ssum[t] = tsum;
        __syncthreads();
        for (int off = 1; off < 256; off <<= 1) {
            int cur = ssum[t];
            int a = (t >= off) ? ssum[t - off] : 0;
            __syncthreads();
            ssum[t] = cur + a;
            __syncthreads();
        }
        const int b0 = ssum[t] - tsum;
        lstart[idx + 0] = b0;
        lstart[idx + 1] = b0 + c0;
        lstart[idx + 2] = b0 + c0 + c1;
        lstart[idx + 3] = b0 + c0 + c1 + c2;
    }
    for (int j = t; j < nbk; j += 256) {
        const int c = lcnt[j];
        gstart[j] = c ? atomicAdd(&gcur[j], c) : 0;
    }
    __syncthreads();

    #pragma unroll
    for (int k = 0; k < 16; ++k) {
        if (bk[k] >= 0) {
            const int slot = lstart[bk[k]] + my[k];
            u32x2 e; e.x = ex[k]; e.y = ey[k];
            stage[slot] = e;
            saddr[slot] = gstart[bk[k]] + my[k];
        }
    }
    __syncthreads();
    for (int s = t; s < cnt; s += 256)
        q[saddr[s]] = stage[s];
}

__global__ void bscatter2(const int* __restrict__ xr, const int* __restrict__ xc,
                          const float* __restrict__ xv, int* __restrict__ gcx,
                          u32x2* __restrict__ qx, int nx, int xblk,
                          const int* __restrict__ ar, const int* __restrict__ ac,
                          const float* __restrict__ av, int* __restrict__ gca,
                          u32x2* __restrict__ qa, int na, int nbk) {
    if ((int)blockIdx.x < xblk)
        bscatter_body(xr, xc, xv, gcx, qx, nx, nbk, (int)blockIdx.x);
    else
        bscatter_body(ar, ac, av, gca, qa, na, nbk, (int)blockIdx.x - xblk);
}

// ------- per-bucket finalize -------

static __device__ __forceinline__ void bfinal_body(
        const u32x2* __restrict__ q, const int* __restrict__ bbase,
        unsigned* __restrict__ edges, int* __restrict__ offsets,
        int N, int nnz, int nbk, int b, bool adj) {
    __shared__ int cnt[RPB], cur[RPB];
    const int t  = (int)threadIdx.x;
    const int gb = bbase[b];
    const int ge = (b + 1 < nbk) ? bbase[b + 1] : nnz;

    cnt[t] = 0;
    __syncthreads();
    for (int i = gb + t; i < ge; i += 256)
        atomicAdd(&cnt[q[i].x >> 17], 1);
    __syncthreads();

    const int c = cnt[t];
    cur[t] = c;
    __syncthreads();
    for (int off = 1; off < 256; off <<= 1) {
        int v = cur[t];
        int a = (t >= off) ? cur[t - off] : 0;
        __syncthreads();
        cur[t] = v + a;
        __syncthreads();
    }
    const int excl = cur[t] - c;
    const int r = b * RPB + t;
    if (r < N) offsets[r] = gb + excl;
    if (b == nbk - 1 && t == 0) offsets[N] = nnz;
    __syncthreads();
    cur[t] = gb + excl;
    __syncthreads();

    for (int i = gb + t; i < ge; i += 256) {
        const u32x2 e = q[i];
        const int rank = atomicAdd(&cur[e.x >> 17], 1);
        const unsigned col = e.x & 0x1FFFFu;
        const float v = __uint_as_float(e.y);
        edges[rank] = adj ? ((col << 15) | (f2bf(v) & 0x7FFFu))
                          : ((col << 16) | f2bf(v));
    }
}

__global__ void bfinalX(const u32x2* __restrict__ qx, const int* __restrict__ bcx,
                        unsigned* __restrict__ ex, int* __restrict__ ox,
                        int N, int nx, int nbk) {
    bfinal_body(qx, bcx, ex, ox, N, nx, nbk, (int)blockIdx.x, false);
}

// ------- spmm1 body (R10 shape): wave per row, lane owns 4 cols -------

static __device__ __forceinline__ void spmm1_body(
        const int* __restrict__ offsets, const unsigned* __restrict__ edges,
        const u32x2* __restrict__ Wb, u32x2* __restrict__ xw, int n, int blk) {
    const int wave = (int)((blk * 256 + (int)threadIdx.x) >> 6);
    const int lane = (int)(threadIdx.x & 63);
    if (wave >= n) return;
    const int s = offsets[wave], e = offsets[wave + 1];

    float4 acc = make_float4(0.f, 0.f, 0.f, 0.f);
    int i = s;
    for (; i + 3 < e; i += 4) {
        const unsigned p0 = __builtin_nontemporal_load(&edges[i]);
        const unsigned p1 = __builtin_nontemporal_load(&edges[i + 1]);
        const unsigned p2 = __builtin_nontemporal_load(&edges[i + 2]);
        const unsigned p3 = __builtin_nontemporal_load(&edges[i + 3]);
        const u32x2 g0 = Wb[(size_t)(p0 >> 16) * 64 + lane];
        const u32x2 g1 = Wb[(size_t)(p1 >> 16) * 64 + lane];
        const u32x2 g2 = Wb[(size_t)(p2 >> 16) * 64 + lane];
        const u32x2 g3 = Wb[(size_t)(p3 >> 16) * 64 + lane];
        const float v0 = blo(p0), v1 = blo(p1), v2 = blo(p2), v3 = blo(p3);
        acc.x += v0 * blo(g0.x) + v1 * blo(g1.x) + v2 * blo(g2.x) + v3 * blo(g3.x);
        acc.y += v0 * bhi(g0.x) + v1 * bhi(g1.x) + v2 * bhi(g2.x) + v3 * bhi(g3.x);
        acc.z += v0 * blo(g0.y) + v1 * blo(g1.y) + v2 * blo(g2.y) + v3 * blo(g3.y);
        acc.w += v0 * bhi(g0.y) + v1 * bhi(g1.y) + v2 * bhi(g2.y) + v3 * bhi(g3.y);
    }
    for (; i < e; ++i) {
        const unsigned p0 = __builtin_nontemporal_load(&edges[i]);
        const u32x2 g0 = Wb[(size_t)(p0 >> 16) * 64 + lane];
        const float v0 = blo(p0);
        acc.x += v0 * blo(g0.x); acc.y += v0 * bhi(g0.x);
        acc.z += v0 * blo(g0.y); acc.w += v0 * bhi(g0.y);
    }
    u32x2 o;
    o.x = f2bf(acc.x) | (f2bf(acc.y) << 16);
    o.y = f2bf(acc.z) | (f2bf(acc.w) << 16);
    xw[(size_t)wave * 64 + lane] = o;            // plain store: keep L2-warm
}

// ------- fusedAS: grid = {bfinal-adj blocks | spmm1 blocks} -------

__global__ void fusedAS(const u32x2* __restrict__ qa, const int* __restrict__ bca,
                        unsigned* __restrict__ ea, int* __restrict__ oa, int na,
                        const int* __restrict__ ox, const unsigned* __restrict__ ex,
                        const u32x2* __restrict__ Wb, u32x2* __restrict__ xw,
                        int N, int nbk) {
    if ((int)blockIdx.x < nbk)
        bfinal_body(qa, bca, ea, oa, N, na, nbk, (int)blockIdx.x, true);
    else
        spmm1_body(ox, ex, Wb, xw, N, (int)blockIdx.x - nbk);
}

// ------- SpMM2 (R10 shape): wave per row, lane owns 4 cols, 8-deep -------

__global__ void spmm2(const int* __restrict__ offsets, const unsigned* __restrict__ edges,
                      const u32x2* __restrict__ xw, f32x4* __restrict__ out, int n) {
    const int wave = (int)((blockIdx.x * blockDim.x + threadIdx.x) >> 6);
    const int lane = (int)(threadIdx.x & 63);
    if (wave >= n) return;
    const int s = offsets[wave], e = offsets[wave + 1];

    float4 acc = make_float4(0.f, 0.f, 0.f, 0.f);
    int i = s;
    for (; i + 7 < e; i += 8) {
        unsigned p[8];
        #pragma unroll
        for (int k = 0; k < 8; ++k) p[k] = __builtin_nontemporal_load(&edges[i + k]);
        u32x2 g[8];
        #pragma unroll
        for (int k = 0; k < 8; ++k) g[k] = xw[(size_t)(p[k] >> 15) * 64 + lane];
        #pragma unroll
        for (int k = 0; k < 8; ++k) {
            const float v = __uint_as_float((p[k] & 0x7FFFu) << 16);
            acc.x += v * blo(g[k].x);
            acc.y += v * bhi(g[k].x);
            acc.z += v * blo(g[k].y);
            acc.w += v * bhi(g[k].y);
        }
    }
    for (; i < e; ++i) {
        const unsigned p0 = __builtin_nontemporal_load(&edges[i]);
        const u32x2 g0 = xw[(size_t)(p0 >> 15) * 64 + lane];
        const float v0 = __uint_as_float((p0 & 0x7FFFu) << 16);
        acc.x += v0 * blo(g0.x); acc.y += v0 * bhi(g0.x);
        acc.z += v0 * blo(g0.y); acc.w += v0 * bhi(g0.y);
    }
    f32x4 o;
    o.x = fmaxf(acc.x, 0.f); o.y = fmaxf(acc.y, 0.f);
    o.z = fmaxf(acc.z, 0.f); o.w = fmaxf(acc.w, 0.f);
    __builtin_nontemporal_store(o, &out[(size_t)wave * 64 + lane]);  // never re-read
}

// ---------------- fallback (atomic) path ----------------

__global__ void spmm_scatter(const int* __restrict__ rows, const int* __restrict__ cols,
                             const float* __restrict__ vals, const float* __restrict__ src,
                             float* __restrict__ dst, int nnz) {
    const int lane  = threadIdx.x & 63;
    const int wave  = (int)((blockIdx.x * blockDim.x + threadIdx.x) >> 6);
    const int nwave = (int)((gridDim.x * blockDim.x) >> 6);
    for (int e = wave; e < nnz; e += nwave) {
        const int r = rows[e];
        const int c = cols[e];
        const float v = vals[e];
        const float4 w = reinterpret_cast<const float4*>(src + (size_t)c * OUT_DIM)[lane];
        float* d = dst + (size_t)r * OUT_DIM + (size_t)lane * 4;
        atomicAdd(d + 0, v * w.x);
        atomicAdd(d + 1, v * w.y);
        atomicAdd(d + 2, v * w.z);
        atomicAdd(d + 3, v * w.w);
    }
}

__global__ void relu_inplace_f4(float4* __restrict__ p, int n4) {
    int i = blockIdx.x * blockDim.x + threadIdx.x;
    int stride = gridDim.x * blockDim.x;
    for (; i < n4; i += stride) {
        float4 v = p[i];
        v.x = fmaxf(v.x, 0.f); v.y = fmaxf(v.y, 0.f);
        v.z = fmaxf(v.z, 0.f); v.w = fmaxf(v.w, 0.f);
        p[i] = v;
    }
}

// -----------------------------------------------------------------------------

static inline size_t al16(size_t x) { return (x + 15) & ~(size_t)15; }

extern "C" void kernel_launch(void* const* d_in, const int* in_sizes, int n_in,
                              void* d_out, int out_size, void* d_ws, size_t ws_size,
                              hipStream_t stream) {
    const int*   x_rows   = (const int*)  d_in[0];
    const int*   x_cols   = (const int*)  d_in[1];
    const float* x_vals   = (const float*)d_in[2];
    const int*   adj_rows = (const int*)  d_in[3];
    const int*   adj_cols = (const int*)  d_in[4];
    const float* adj_vals = (const float*)d_in[5];
    const float* W        = (const float*)d_in[6];

    const int nnz_x   = in_sizes[0];
    const int nnz_adj = in_sizes[3];
    const int N       = out_size / OUT_DIM;          // 100000
    const int IN_DIM  = in_sizes[6] / OUT_DIM;       // 1024
    const int nbk     = (N + RPB - 1) / RPB;         // 391 buckets

    float* out = (float*)d_out;
    char*  ws  = (char*)d_ws;

    // ---- workspace layout ----
    const size_t xw_bytes  = al16((size_t)N * OUT_DIM * 2);        // bf16 xw
    const size_t wb_bytes  = al16((size_t)IN_DIM * OUT_DIM * 2);   // bf16 W
    const size_t off_bytes = al16((size_t)(N + 1) * 4);
    const size_t b_bytes   = al16((size_t)nbk * 4);
    const size_t qx_bytes  = al16((size_t)nnz_x * 8);
    const size_t qa_bytes  = al16((size_t)nnz_adj * 8);
    const size_t ex_bytes  = al16((size_t)nnz_x * 4);
    const size_t ea_bytes  = al16((size_t)nnz_adj * 4);
    const size_t need = xw_bytes + wb_bytes + 2 * off_bytes + 4 * b_bytes
                      + qx_bytes + qa_bytes + ex_bytes + ea_bytes;

    if (ws_size < need || nbk > MAXB || N > (1 << 17) || IN_DIM > (1 << 16)) {
        float* xwf = (float*)ws;
        (void)hipMemsetAsync(xwf, 0, (size_t)out_size * 4, stream);
        (void)hipMemsetAsync(out, 0, (size_t)out_size * 4, stream);
        spmm_scatter<<<8192, 256, 0, stream>>>(x_rows, x_cols, x_vals, W, xwf, nnz_x);
        spmm_scatter<<<8192, 256, 0, stream>>>(adj_rows, adj_cols, adj_vals, xwf, out, nnz_adj);
        relu_inplace_f4<<<2048, 256, 0, stream>>>((float4*)out, out_size / 4);
        return;
    }

    char* p = ws;
    u32x2*    xw      = (u32x2*)p;    p += xw_bytes;
    u32x2*    Wb      = (u32x2*)p;    p += wb_bytes;
    int*      off_x   = (int*)p;      p += off_bytes;
    int*      off_a   = (int*)p;      p += off_bytes;
    int*      bcx     = (int*)p;      p += b_bytes;
    int*      bca     = (int*)p;      p += b_bytes;   // contiguous with bcx
    int*      gcx     = (int*)p;      p += b_bytes;
    int*      gca     = (int*)p;      p += b_bytes;
    u32x2*    qx      = (u32x2*)p;    p += qx_bytes;
    u32x2*    qa      = (u32x2*)p;    p += qa_bytes;
    unsigned* edges_x = (unsigned*)p; p += ex_bytes;
    unsigned* edges_a = (unsigned*)p; p += ea_bytes;

    const int spmm_blocks = (N + 3) / 4;                   // 4 waves / block
    const int n_wb        = IN_DIM * (OUT_DIM / 4);        // u32x2 entries in Wb
    const int scat_x_blk  = (nnz_x + CHUNK - 1) / CHUNK;
    const int scat_a_blk  = (nnz_adj + CHUNK - 1) / CHUNK;

    // ---- bucket sort (both matrices) ----
    (void)hipMemsetAsync(bcx, 0, 2 * b_bytes, stream);     // bcx + bca
    bhist2<<<2048, 256, 0, stream>>>(x_rows, nnz_x, adj_rows, nnz_adj,
                                     bcx, bca, W, Wb, n_wb, nbk);
    bscan2<<<2, MAXB, 0, stream>>>(bcx, bca, gcx, gca, nbk);
    bscatter2<<<scat_x_blk + scat_a_blk, 256, 0, stream>>>(
        x_rows, x_cols, x_vals, gcx, qx, nnz_x, scat_x_blk,
        adj_rows, adj_cols, adj_vals, gca, qa, nnz_adj, nbk);

    // ---- finalize x, then {finalize adj || spmm1}, then spmm2 ----
    bfinalX<<<nbk, RPB, 0, stream>>>(qx, bcx, edges_x, off_x, N, nnz_x, nbk);
    fusedAS<<<nbk + spmm_blocks, 256, 0, stream>>>(qa, bca, edges_a, off_a, nnz_adj,
                                                   off_x, edges_x, Wb, xw, N, nbk);
    spmm2<<<spmm_blocks, 256, 0, stream>>>(off_a, edges_a, xw, (f32x4*)out, N);
}

// Round 17
// 543.397 us; speedup vs baseline: 1.0478x; 1.0478x over previous
//
#include <hip/hip_runtime.h>

// GCN sparse conv: out = relu( sparse(adj) @ ( sparse(x) @ W ) )
// R15 champion (best measured: 543us). Bucket counting sort (256 rows/bucket):
//   bhist2:    LDS bucket histogram, int4-vectorized row loads (+W->bf16)
//   bscan2:    exclusive scan of bucket counts -> bases + cursors
//   bscatter2: 4096-edge chunks (grid split x|adj); int4/float4 COO reads;
//              LDS hist -> ONE global fetch-add per (block,bucket); LDS
//              re-rank; coalesced flush to bucket-grouped q.
//   bfinal2:   one block per bucket (grid split x|adj): per-row LDS
//              count/scan/re-rank -> CSR offsets + packed 4B edges.
// SpMM (half-wave paired): lanes 0-31 gather edge i's source row in 16B
// slices, lanes 32-63 edge i+1; lane owns an 8-col slice; __shfl_xor(32)
// merges halves. spmm2 is L2-fill service-rate bound (~3.4TB/s, 52% hit
// structural regardless of footprint) - the floor.
// Edge words 4B: x = col<<16 | bf16(val); adj = col<<15 | bf15(val>=0).
// xw bf16 plain stores (L2-warm for spmm2); NT store only for final out.

constexpr int OUT_DIM = 256;
constexpr int RPB     = 256;     // rows per bucket
constexpr int RPB_SH  = 8;
constexpr int MAXB    = 1024;    // max buckets (N <= 262144)
constexpr int CHUNK   = 4096;    // edges per bscatter block

typedef float        f32x4 __attribute__((ext_vector_type(4)));
typedef unsigned int u32x2 __attribute__((ext_vector_type(2)));
typedef unsigned int u32x4 __attribute__((ext_vector_type(4)));
typedef int          i32x4 __attribute__((ext_vector_type(4)));

static __device__ __forceinline__ unsigned f2bf(float f) {
    unsigned u = __float_as_uint(f);
    return (u + 0x7FFFu + ((u >> 16) & 1u)) >> 16;   // round-nearest-even
}
static __device__ __forceinline__ float blo(unsigned w) { return __uint_as_float(w << 16); }
static __device__ __forceinline__ float bhi(unsigned w) { return __uint_as_float(w & 0xFFFF0000u); }

// ------- bucket histogram (both matrices, vectorized) + W->bf16 -------

__global__ void bhist2(const int* __restrict__ xr, int nx,
                       const int* __restrict__ ar, int na,
                       int* __restrict__ bcx, int* __restrict__ bca,
                       const float* __restrict__ W, u32x2* __restrict__ Wb,
                       int n_wb, int nbk) {
    __shared__ int hx[MAXB], ha[MAXB];
    const int t = (int)threadIdx.x;
    for (int j = t; j < nbk; j += 256) { hx[j] = 0; ha[j] = 0; }
    __syncthreads();
    const int gid = (int)(blockIdx.x * blockDim.x + threadIdx.x);
    const int stride = (int)(gridDim.x * blockDim.x);
    const int nx4 = nx >> 2, na4 = na >> 2;
    for (int i = gid; i < nx4; i += stride) {
        const i32x4 r = __builtin_nontemporal_load(reinterpret_cast<const i32x4*>(xr) + i);
        atomicAdd(&hx[r.x >> RPB_SH], 1); atomicAdd(&hx[r.y >> RPB_SH], 1);
        atomicAdd(&hx[r.z >> RPB_SH], 1); atomicAdd(&hx[r.w >> RPB_SH], 1);
    }
    for (int i = nx4 * 4 + gid; i < nx; i += stride) atomicAdd(&hx[xr[i] >> RPB_SH], 1);
    for (int i = gid; i < na4; i += stride) {
        const i32x4 r = __builtin_nontemporal_load(reinterpret_cast<const i32x4*>(ar) + i);
        atomicAdd(&ha[r.x >> RPB_SH], 1); atomicAdd(&ha[r.y >> RPB_SH], 1);
        atomicAdd(&ha[r.z >> RPB_SH], 1); atomicAdd(&ha[r.w >> RPB_SH], 1);
    }
    for (int i = na4 * 4 + gid; i < na; i += stride) atomicAdd(&ha[ar[i] >> RPB_SH], 1);
    for (int i = gid; i < n_wb; i += stride) {
        const float4 w = reinterpret_cast<const float4*>(W)[i];
        u32x2 o;
        o.x = f2bf(w.x) | (f2bf(w.y) << 16);
        o.y = f2bf(w.z) | (f2bf(w.w) << 16);
        Wb[i] = o;
    }
    __syncthreads();
    for (int j = t; j < nbk; j += 256) {
        if (hx[j]) atomicAdd(&bcx[j], hx[j]);
        if (ha[j]) atomicAdd(&bca[j], ha[j]);
    }
}

// ------- exclusive scan of bucket counts (in place) + cursor init -------

__global__ void bscan2(int* __restrict__ bx, int* __restrict__ ba,
                       int* __restrict__ gx, int* __restrict__ ga, int nbk) {
    __shared__ int sh[MAXB];
    int* bs = (blockIdx.x == 0) ? bx : ba;
    int* gc = (blockIdx.x == 0) ? gx : ga;
    const int t = (int)threadIdx.x;
    const int v = (t < nbk) ? bs[t] : 0;
    sh[t] = v;
    __syncthreads();
    for (int off = 1; off < MAXB; off <<= 1) {
        int cur = sh[t];
        int a = (t >= off) ? sh[t - off] : 0;
        __syncthreads();
        sh[t] = cur + a;
        __syncthreads();
    }
    if (t < nbk) {
        const int e = sh[t] - v;   // exclusive
        bs[t] = e;
        gc[t] = e;
    }
}

// ------- aggregated bucket scatter (grid split x | adj), vectorized reads -------
// q entry: .x = rowInBucket(8b)<<17 | col(17b);  .y = f32 val bits.

static __device__ __forceinline__ void bscatter_body(
        const int* __restrict__ rows, const int* __restrict__ cols,
        const float* __restrict__ vals, int* __restrict__ gcur,
        u32x2* __restrict__ q, int nnz, int nbk, int blk) {
    __shared__ u32x2 stage[CHUNK];
    __shared__ int   saddr[CHUNK];
    __shared__ int   lcnt[MAXB], lstart[MAXB], gstart[MAXB];
    __shared__ int   ssum[256];
    const int t    = (int)threadIdx.x;
    const int base = blk * CHUNK;
    const int cnt  = min(CHUNK, nnz - base);

    for (int j = t; j < nbk; j += 256) lcnt[j] = 0;
    __syncthreads();

    int   rr[16] __attribute__((aligned(16)));
    int   cc[16] __attribute__((aligned(16)));
    float vv[16] __attribute__((aligned(16)));
    unsigned ex[16], ey[16];
    int my[16], bk[16];
    const int i0 = base + t * 16;
    if (i0 + 16 <= nnz) {
        #pragma unroll
        for (int g = 0; g < 4; ++g) {
            reinterpret_cast<i32x4*>(rr)[g] =
                __builtin_nontemporal_load(reinterpret_cast<const i32x4*>(rows + i0) + g);
            reinterpret_cast<i32x4*>(cc)[g] =
                __builtin_nontemporal_load(reinterpret_cast<const i32x4*>(cols + i0) + g);
            reinterpret_cast<f32x4*>(vv)[g] =
                __builtin_nontemporal_load(reinterpret_cast<const f32x4*>(vals + i0) + g);
        }
    } else {
        #pragma unroll
        for (int k = 0; k < 16; ++k) {
            if (i0 + k < nnz) { rr[k] = rows[i0 + k]; cc[k] = cols[i0 + k]; vv[k] = vals[i0 + k]; }
            else              { rr[k] = 0; cc[k] = 0; vv[k] = 0.f; }
        }
    }
    #pragma unroll
    for (int k = 0; k < 16; ++k) {
        bk[k] = -1;
        if (i0 + k < nnz) {
            const int r = rr[k];
            bk[k] = r >> RPB_SH;
            ex[k] = ((unsigned)(r & (RPB - 1)) << 17) | (unsigned)cc[k];
            ey[k] = __float_as_uint(vv[k]);
            my[k] = atomicAdd(&lcnt[bk[k]], 1);
        }
    }
    __syncthreads();

    {   // local exclusive scan of lcnt -> lstart (4 elems/thread)
        const int idx = t * 4;
        const int c0 = (idx + 0 < nbk) ? lcnt[idx + 0] : 0;
        const int c1 = (idx + 1 < nbk) ? lcnt[idx + 1] : 0;
        const int c2 = (idx + 2 < nbk) ? lcnt[idx + 2] : 0;
        const int c3 = (idx + 3 < nbk) ? lcnt[idx + 3] : 0;
        const int tsum = c0 + c1 + c2 + c3;
        ssum[t] = tsum;
        __syncthreads();
        for (int off = 1; off < 256; off <<= 1) {
            int cur = ssum[t];
            int a = (t >= off) ? ssum[t - off] : 0;
            __syncthreads();
            ssum[t] = cur + a;
            __syncthreads();
        }
        const int b0 = ssum[t] - tsum;
        lstart[idx + 0] = b0;
        lstart[idx + 1] = b0 + c0;
        lstart[idx + 2] = b0 + c0 + c1;
        lstart[idx + 3] = b0 + c0 + c1 + c2;
    }
    for (int j = t; j < nbk; j += 256) {
        const int c = lcnt[j];
        gstart[j] = c ? atomicAdd(&gcur[j], c) : 0;
    }
    __syncthreads();

    #pragma unroll
    for (int k = 0; k < 16; ++k) {
        if (bk[k] >= 0) {
            const int slot = lstart[bk[k]] + my[k];
            u32x2 e; e.x = ex[k]; e.y = ey[k];
            stage[slot] = e;
            saddr[slot] = gstart[bk[k]] + my[k];
        }
    }
    __syncthreads();
    for (int s = t; s < cnt; s += 256)
        q[saddr[s]] = stage[s];
}

__global__ void bscatter2(const int* __restrict__ xr, const int* __restrict__ xc,
                          const float* __restrict__ xv, int* __restrict__ gcx,
                          u32x2* __restrict__ qx, int nx, int xblk,
                          const int* __restrict__ ar, const int* __restrict__ ac,
                          const float* __restrict__ av, int* __restrict__ gca,
                          u32x2* __restrict__ qa, int na, int nbk) {
    if ((int)blockIdx.x < xblk)
        bscatter_body(xr, xc, xv, gcx, qx, nx, nbk, (int)blockIdx.x);
    else
        bscatter_body(ar, ac, av, gca, qa, na, nbk, (int)blockIdx.x - xblk);
}

// ------- per-bucket finalize (grid split x | adj) -------

static __device__ __forceinline__ void bfinal_body(
        const u32x2* __restrict__ q, const int* __restrict__ bbase,
        unsigned* __restrict__ edges, int* __restrict__ offsets,
        int N, int nnz, int nbk, int b, bool adj) {
    __shared__ int cnt[RPB], cur[RPB];
    const int t  = (int)threadIdx.x;
    const int gb = bbase[b];
    const int ge = (b + 1 < nbk) ? bbase[b + 1] : nnz;

    cnt[t] = 0;
    __syncthreads();
    for (int i = gb + t; i < ge; i += 256)
        atomicAdd(&cnt[q[i].x >> 17], 1);
    __syncthreads();

    const int c = cnt[t];
    cur[t] = c;
    __syncthreads();
    for (int off = 1; off < 256; off <<= 1) {
        int v = cur[t];
        int a = (t >= off) ? cur[t - off] : 0;
        __syncthreads();
        cur[t] = v + a;
        __syncthreads();
    }
    const int excl = cur[t] - c;
    const int r = b * RPB + t;
    if (r < N) offsets[r] = gb + excl;
    if (b == nbk - 1 && t == 0) offsets[N] = nnz;
    __syncthreads();
    cur[t] = gb + excl;
    __syncthreads();

    for (int i = gb + t; i < ge; i += 256) {
        const u32x2 e = q[i];
        const int rank = atomicAdd(&cur[e.x >> 17], 1);
        const unsigned col = e.x & 0x1FFFFu;
        const float v = __uint_as_float(e.y);
        edges[rank] = adj ? ((col << 15) | (f2bf(v) & 0x7FFFu))
                          : ((col << 16) | f2bf(v));
    }
}

__global__ void bfinal2(const u32x2* __restrict__ qx, const int* __restrict__ bcx,
                        unsigned* __restrict__ ex, int* __restrict__ ox, int nx,
                        const u32x2* __restrict__ qa, const int* __restrict__ bca,
                        unsigned* __restrict__ ea, int* __restrict__ oa, int na,
                        int N, int nbk) {
    if ((int)blockIdx.x < nbk)
        bfinal_body(qx, bcx, ex, ox, N, nx, nbk, (int)blockIdx.x, false);
    else
        bfinal_body(qa, bca, ea, oa, N, na, nbk, (int)blockIdx.x - nbk, true);
}

// ------- SpMM1 (paired): xw(bf16) = sparse(x) @ Wb(bf16) -------

__global__ void spmm1(const int* __restrict__ offsets, const unsigned* __restrict__ edges,
                      const u32x4* __restrict__ Wb4, u32x2* __restrict__ xw, int n) {
    const int wave = (int)((blockIdx.x * blockDim.x + threadIdx.x) >> 6);
    const int lane = (int)(threadIdx.x & 63);
    if (wave >= n) return;
    const int half = lane >> 5, sl = lane & 31;
    const int s = offsets[wave], e = offsets[wave + 1];

    float a0 = 0.f, a1 = 0.f, a2 = 0.f, a3 = 0.f, a4 = 0.f, a5 = 0.f, a6 = 0.f, a7 = 0.f;
    int i = s;
    for (; i + 15 < e; i += 16) {
        unsigned p[8];
        #pragma unroll
        for (int j = 0; j < 8; ++j) p[j] = __builtin_nontemporal_load(&edges[i + 2 * j + half]);
        u32x4 g[8];
        #pragma unroll
        for (int j = 0; j < 8; ++j) g[j] = Wb4[(size_t)(p[j] >> 16) * 32 + sl];
        #pragma unroll
        for (int j = 0; j < 8; ++j) {
            const float v = blo(p[j]);
            a0 += v * blo(g[j].x); a1 += v * bhi(g[j].x);
            a2 += v * blo(g[j].y); a3 += v * bhi(g[j].y);
            a4 += v * blo(g[j].z); a5 += v * bhi(g[j].z);
            a6 += v * blo(g[j].w); a7 += v * bhi(g[j].w);
        }
    }
    for (; i < e; i += 2) {
        const int idx = i + half;
        const bool ok = idx < e;
        const unsigned p = ok ? __builtin_nontemporal_load(&edges[idx]) : 0u;
        const u32x4 g = Wb4[(size_t)(p >> 16) * 32 + sl];
        const float v = ok ? blo(p) : 0.f;
        a0 += v * blo(g.x); a1 += v * bhi(g.x);
        a2 += v * blo(g.y); a3 += v * bhi(g.y);
        a4 += v * blo(g.z); a5 += v * bhi(g.z);
        a6 += v * blo(g.w); a7 += v * bhi(g.w);
    }
    a0 += __shfl_xor(a0, 32); a1 += __shfl_xor(a1, 32);
    a2 += __shfl_xor(a2, 32); a3 += __shfl_xor(a3, 32);
    a4 += __shfl_xor(a4, 32); a5 += __shfl_xor(a5, 32);
    a6 += __shfl_xor(a6, 32); a7 += __shfl_xor(a7, 32);
    u32x2 o;
    if (half == 0) { o.x = f2bf(a0) | (f2bf(a1) << 16); o.y = f2bf(a2) | (f2bf(a3) << 16); }
    else           { o.x = f2bf(a4) | (f2bf(a5) << 16); o.y = f2bf(a6) | (f2bf(a7) << 16); }
    xw[(size_t)wave * 64 + 2 * sl + half] = o;     // plain store: keep L2-warm
}

// ------- SpMM2 (paired): out(f32) = relu( sparse(adj) @ xw(bf16) ) -------

__global__ void spmm2(const int* __restrict__ offsets, const unsigned* __restrict__ edges,
                      const u32x4* __restrict__ xw4, f32x4* __restrict__ out, int n) {
    const int wave = (int)((blockIdx.x * blockDim.x + threadIdx.x) >> 6);
    const int lane = (int)(threadIdx.x & 63);
    if (wave >= n) return;
    const int half = lane >> 5, sl = lane & 31;
    const int s = offsets[wave], e = offsets[wave + 1];

    float a0 = 0.f, a1 = 0.f, a2 = 0.f, a3 = 0.f, a4 = 0.f, a5 = 0.f, a6 = 0.f, a7 = 0.f;
    int i = s;
    for (; i + 15 < e; i += 16) {
        unsigned p[8];
        #pragma unroll
        for (int j = 0; j < 8; ++j) p[j] = __builtin_nontemporal_load(&edges[i + 2 * j + half]);
        u32x4 g[8];
        #pragma unroll
        for (int j = 0; j < 8; ++j) g[j] = xw4[(size_t)(p[j] >> 15) * 32 + sl];
        #pragma unroll
        for (int j = 0; j < 8; ++j) {
            const float v = __uint_as_float((p[j] & 0x7FFFu) << 16);
            a0 += v * blo(g[j].x); a1 += v * bhi(g[j].x);
            a2 += v * blo(g[j].y); a3 += v * bhi(g[j].y);
            a4 += v * blo(g[j].z); a5 += v * bhi(g[j].z);
            a6 += v * blo(g[j].w); a7 += v * bhi(g[j].w);
        }
    }
    for (; i < e; i += 2) {
        const int idx = i + half;
        const bool ok = idx < e;
        const unsigned p = ok ? __builtin_nontemporal_load(&edges[idx]) : 0u;
        const u32x4 g = xw4[(size_t)(p >> 15) * 32 + sl];
        const float v = ok ? __uint_as_float((p & 0x7FFFu) << 16) : 0.f;
        a0 += v * blo(g.x); a1 += v * bhi(g.x);
        a2 += v * blo(g.y); a3 += v * bhi(g.y);
        a4 += v * blo(g.z); a5 += v * bhi(g.z);
        a6 += v * blo(g.w); a7 += v * bhi(g.w);
    }
    a0 += __shfl_xor(a0, 32); a1 += __shfl_xor(a1, 32);
    a2 += __shfl_xor(a2, 32); a3 += __shfl_xor(a3, 32);
    a4 += __shfl_xor(a4, 32); a5 += __shfl_xor(a5, 32);
    a6 += __shfl_xor(a6, 32); a7 += __shfl_xor(a7, 32);
    f32x4 o;
    if (half == 0) { o.x = fmaxf(a0, 0.f); o.y = fmaxf(a1, 0.f);
                     o.z = fmaxf(a2, 0.f); o.w = fmaxf(a3, 0.f); }
    else           { o.x = fmaxf(a4, 0.f); o.y = fmaxf(a5, 0.f);
                     o.z = fmaxf(a6, 0.f); o.w = fmaxf(a7, 0.f); }
    __builtin_nontemporal_store(o, &out[(size_t)wave * 64 + 2 * sl + half]);
}

// ---------------- fallback (atomic) path ----------------

__global__ void spmm_scatter(const int* __restrict__ rows, const int* __restrict__ cols,
                             const float* __restrict__ vals, const float* __restrict__ src,
                             float* __restrict__ dst, int nnz) {
    const int lane  = threadIdx.x & 63;
    const int wave  = (int)((blockIdx.x * blockDim.x + threadIdx.x) >> 6);
    const int nwave = (int)((gridDim.x * blockDim.x) >> 6);
    for (int e = wave; e < nnz; e += nwave) {
        const int r = rows[e];
        const int c = cols[e];
        const float v = vals[e];
        const float4 w = reinterpret_cast<const float4*>(src + (size_t)c * OUT_DIM)[lane];
        float* d = dst + (size_t)r * OUT_DIM + (size_t)lane * 4;
        atomicAdd(d + 0, v * w.x);
        atomicAdd(d + 1, v * w.y);
        atomicAdd(d + 2, v * w.z);
        atomicAdd(d + 3, v * w.w);
    }
}

__global__ void relu_inplace_f4(float4* __restrict__ p, int n4) {
    int i = blockIdx.x * blockDim.x + threadIdx.x;
    int stride = gridDim.x * blockDim.x;
    for (; i < n4; i += stride) {
        float4 v = p[i];
        v.x = fmaxf(v.x, 0.f); v.y = fmaxf(v.y, 0.f);
        v.z = fmaxf(v.z, 0.f); v.w = fmaxf(v.w, 0.f);
        p[i] = v;
    }
}

// -----------------------------------------------------------------------------

static inline size_t al16(size_t x) { return (x + 15) & ~(size_t)15; }

extern "C" void kernel_launch(void* const* d_in, const int* in_sizes, int n_in,
                              void* d_out, int out_size, void* d_ws, size_t ws_size,
                              hipStream_t stream) {
    const int*   x_rows   = (const int*)  d_in[0];
    const int*   x_cols   = (const int*)  d_in[1];
    const float* x_vals   = (const float*)d_in[2];
    const int*   adj_rows = (const int*)  d_in[3];
    const int*   adj_cols = (const int*)  d_in[4];
    const float* adj_vals = (const float*)d_in[5];
    const float* W        = (const float*)d_in[6];

    const int nnz_x   = in_sizes[0];
    const int nnz_adj = in_sizes[3];
    const int N       = out_size / OUT_DIM;          // 100000
    const int IN_DIM  = in_sizes[6] / OUT_DIM;       // 1024
    const int nbk     = (N + RPB - 1) / RPB;         // 391 buckets

    float* out = (float*)d_out;
    char*  ws  = (char*)d_ws;

    // ---- workspace layout ----
    const size_t xw_bytes  = al16((size_t)N * OUT_DIM * 2);        // bf16 xw
    const size_t wb_bytes  = al16((size_t)IN_DIM * OUT_DIM * 2);   // bf16 W
    const size_t off_bytes = al16((size_t)(N + 1) * 4);
    const size_t b_bytes   = al16((size_t)nbk * 4);
    const size_t qx_bytes  = al16((size_t)nnz_x * 8);
    const size_t qa_bytes  = al16((size_t)nnz_adj * 8);
    const size_t ex_bytes  = al16((size_t)nnz_x * 4);
    const size_t ea_bytes  = al16((size_t)nnz_adj * 4);
    const size_t need = xw_bytes + wb_bytes + 2 * off_bytes + 4 * b_bytes
                      + qx_bytes + qa_bytes + ex_bytes + ea_bytes;

    if (ws_size < need || nbk > MAXB || N > (1 << 17) || IN_DIM > (1 << 16)) {
        float* xwf = (float*)ws;
        (void)hipMemsetAsync(xwf, 0, (size_t)out_size * 4, stream);
        (void)hipMemsetAsync(out, 0, (size_t)out_size * 4, stream);
        spmm_scatter<<<8192, 256, 0, stream>>>(x_rows, x_cols, x_vals, W, xwf, nnz_x);
        spmm_scatter<<<8192, 256, 0, stream>>>(adj_rows, adj_cols, adj_vals, xwf, out, nnz_adj);
        relu_inplace_f4<<<2048, 256, 0, stream>>>((float4*)out, out_size / 4);
        return;
    }

    char* p = ws;
    u32x2*    xw      = (u32x2*)p;    p += xw_bytes;
    u32x2*    Wb      = (u32x2*)p;    p += wb_bytes;
    int*      off_x   = (int*)p;      p += off_bytes;
    int*      off_a   = (int*)p;      p += off_bytes;
    int*      bcx     = (int*)p;      p += b_bytes;
    int*      bca     = (int*)p;      p += b_bytes;   // contiguous with bcx
    int*      gcx     = (int*)p;      p += b_bytes;
    int*      gca     = (int*)p;      p += b_bytes;
    u32x2*    qx      = (u32x2*)p;    p += qx_bytes;
    u32x2*    qa      = (u32x2*)p;    p += qa_bytes;
    unsigned* edges_x = (unsigned*)p; p += ex_bytes;
    unsigned* edges_a = (unsigned*)p; p += ea_bytes;

    const int spmm_blocks = (N + 3) / 4;                   // 4 waves / block
    const int n_wb        = IN_DIM * (OUT_DIM / 4);        // u32x2 entries in Wb
    const int scat_x_blk  = (nnz_x + CHUNK - 1) / CHUNK;
    const int scat_a_blk  = (nnz_adj + CHUNK - 1) / CHUNK;

    // ---- bucket sort (both matrices) ----
    (void)hipMemsetAsync(bcx, 0, 2 * b_bytes, stream);     // bcx + bca
    bhist2<<<2048, 256, 0, stream>>>(x_rows, nnz_x, adj_rows, nnz_adj,
                                     bcx, bca, W, Wb, n_wb, nbk);
    bscan2<<<2, MAXB, 0, stream>>>(bcx, bca, gcx, gca, nbk);
    bscatter2<<<scat_x_blk + scat_a_blk, 256, 0, stream>>>(
        x_rows, x_cols, x_vals, gcx, qx, nnz_x, scat_x_blk,
        adj_rows, adj_cols, adj_vals, gca, qa, nnz_adj, nbk);
    bfinal2<<<2 * nbk, RPB, 0, stream>>>(qx, bcx, edges_x, off_x, nnz_x,
                                         qa, bca, edges_a, off_a, nnz_adj, N, nbk);

    // ---- SpMMs (half-wave paired) ----
    spmm1<<<spmm_blocks, 256, 0, stream>>>(off_x, edges_x, (const u32x4*)Wb, xw, N);
    spmm2<<<spmm_blocks, 256, 0, stream>>>(off_a, edges_a, (const u32x4*)xw, (f32x4*)out, N);
}